// Round 1
// baseline (2593.610 us; speedup 1.0000x reference)
//
#include <hip/hip_runtime.h>
#include <cstdint>
#include <cstddef>

typedef __bf16 bf16;
typedef __attribute__((ext_vector_type(8))) __bf16 bf16x8;
typedef __attribute__((ext_vector_type(4))) float f32x4;

#define B_TOT 8192

// ---------------- async global->LDS (16B per lane) ----------------
__device__ __forceinline__ void gload16(const void* g, void* l) {
  __builtin_amdgcn_global_load_lds(
      (__attribute__((address_space(1))) void*)g,
      (__attribute__((address_space(3))) void*)l, 16, 0, 0);
}

// ---------------- block reduction helper (256 threads, 4 waves) ----------------
__device__ __forceinline__ void block_sum2(float& a, float& b, float* lds8) {
#pragma unroll
  for (int o = 32; o; o >>= 1) {
    a += __shfl_xor(a, o, 64);
    b += __shfl_xor(b, o, 64);
  }
  int w = threadIdx.x >> 6;
  if ((threadIdx.x & 63) == 0) { lds8[w] = a; lds8[4 + w] = b; }
  __syncthreads();
  a = lds8[0] + lds8[1] + lds8[2] + lds8[3];
  b = lds8[4] + lds8[5] + lds8[6] + lds8[7];
  __syncthreads();
}

// ---------------- prep: age-sort gather, gseq/lpool/zb/Lg ----------------
__global__ __launch_bounds__(256) void prep_kernel(
    const float* __restrict__ z, const float* __restrict__ buf,
    const int* __restrict__ mask, const int* __restrict__ idxs,
    bf16* __restrict__ gseq, bf16* __restrict__ lpool, bf16* __restrict__ zb,
    int* __restrict__ Lg, int b0)
{
  const int bl = blockIdx.x;
  const int b  = b0 + bl;
  __shared__ int ord[12];
  __shared__ int s_nv;
  if (threadIdx.x == 0) {
    int id = idxs[b];
    int nv = 0;
    // enumerate ages descending -> oldest-first order of valid slots
    for (int a = 11; a >= 0; --a) {
      int pos = id - a; if (pos < 0) pos += 12;
      if (mask[b * 12 + pos]) ord[nv++] = pos;
    }
    s_nv = nv;
    Lg[bl] = (nv < 11 ? nv : 11) + 1;
  }
  __syncthreads();
  const int nv = s_nv;
  const int hg = (nv < 11 ? nv : 11);
  const int hl = (nv < 4 ? nv : 4);
  const float ldenom = 1.0f / (float)(hl + 1);
  for (int c = threadIdx.x; c < 768; c += 256) {
    float zv = z[(long)b * 768 + c];
    zb[(long)bl * 768 + c] = (bf16)zv;
    float ls = 0.0f;
#pragma unroll
    for (int s = 0; s < 12; ++s) {
      float v = 0.0f;
      if (s < hg) v = buf[((long)b * 12 + ord[s]) * 768 + c];
      else if (s == 11) v = zv;
      gseq[((long)bl * 12 + s) * 768 + c] = (bf16)v;
      if (s < hl) ls += v;  // hist rows (hl <= hg always)
    }
    if (nv >= 4) ls += zv;  // current included only when local hist is full
    lpool[(long)bl * 768 + c] = (bf16)(ls * ldenom);
  }
}

// ---------------- weight transpose f32(K,N) -> bf16(N,K) ----------------
__global__ __launch_bounds__(256) void transpose_bf16(
    const float* __restrict__ W, bf16* __restrict__ Wt, int K, int N)
{
  __shared__ float tile[32][33];
  int bn = blockIdx.x * 32;   // N
  int bk = blockIdx.y * 32;   // K
  int tx = threadIdx.x & 31;
  int ty0 = threadIdx.x >> 5; // 0..7
  for (int ty = ty0; ty < 32; ty += 8)
    tile[ty][tx] = W[(long)(bk + ty) * N + bn + tx];
  __syncthreads();
  for (int ty = ty0; ty < 32; ty += 8)
    Wt[(long)(bn + ty) * K + bk + tx] = (bf16)tile[tx][ty];
}

__global__ __launch_bounds__(256) void pack3_kernel(
    const float* __restrict__ a, const float* __restrict__ b,
    const float* __restrict__ c, float* __restrict__ out)
{
  int t = blockIdx.x * blockDim.x + threadIdx.x;
  if (t < 768) out[t] = a[t];
  else if (t < 1536) out[t] = b[t - 768];
  else if (t < 2304) out[t] = c[t - 1536];
}

// ---------------- MFMA GEMM: C(M,N) = A(M,K) @ Bt(N,K)^T + bias ----------------
// 128x128 tile, BK=32, 4 waves in 2x2, each wave 4x4 of 16x16x32 bf16 MFMA.
// LDS staged via global_load_lds(16B) with XOR chunk swizzle swz(r)=(r>>1)&3.
__global__ __launch_bounds__(256, 2) void gemm_bt(
    const bf16* __restrict__ A, const bf16* __restrict__ Bt,
    const float* __restrict__ bias, void* __restrict__ C,
    int K, int N, int act, int outf32)
{
  __shared__ __align__(16) bf16 As[128 * 32];
  __shared__ __align__(16) bf16 Bs[128 * 32];
  const int tid  = threadIdx.x;
  const int wave = tid >> 6;
  const int lane = tid & 63;
  const long m0 = (long)blockIdx.y * 128;
  const long n0 = (long)blockIdx.x * 128;
  const int wm = (wave >> 1) * 64;
  const int wn = (wave & 1) * 64;

  // staging source maps (each wave stages two contiguous 1KB LDS segments)
  const int r0  = (wave * 2 + 0) * 16 + (lane >> 2);
  const int r1  = (wave * 2 + 1) * 16 + (lane >> 2);
  const int kc0 = (lane & 3) ^ ((r0 >> 1) & 3);
  const int kc1 = (lane & 3) ^ ((r1 >> 1) & 3);
  const bf16* Ag0 = A + (m0 + r0) * K + kc0 * 8;
  const bf16* Ag1 = A + (m0 + r1) * K + kc1 * 8;
  const bf16* Bg0 = Bt + (n0 + r0) * K + kc0 * 8;
  const bf16* Bg1 = Bt + (n0 + r1) * K + kc1 * 8;
  bf16* Al0 = As + (wave * 2 + 0) * 512 + lane * 8;
  bf16* Al1 = As + (wave * 2 + 1) * 512 + lane * 8;
  bf16* Bl0 = Bs + (wave * 2 + 0) * 512 + lane * 8;
  bf16* Bl1 = Bs + (wave * 2 + 1) * 512 + lane * 8;

  f32x4 acc[4][4] = {};
  const int i16  = lane & 15;
  const int quad = lane >> 4;

  for (int kt = 0; kt < K; kt += 32) {
    __syncthreads();
    gload16(Ag0 + kt, Al0);
    gload16(Ag1 + kt, Al1);
    gload16(Bg0 + kt, Bl0);
    gload16(Bg1 + kt, Bl1);
    __syncthreads();

    bf16x8 af[4], bfr[4];
#pragma unroll
    for (int i = 0; i < 4; ++i) {
      int r = wm + i * 16 + i16;
      af[i] = *(const bf16x8*)(As + r * 32 + ((quad ^ ((r >> 1) & 3)) * 8));
    }
#pragma unroll
    for (int j = 0; j < 4; ++j) {
      int r = wn + j * 16 + i16;
      bfr[j] = *(const bf16x8*)(Bs + r * 32 + ((quad ^ ((r >> 1) & 3)) * 8));
    }
#pragma unroll
    for (int i = 0; i < 4; ++i)
#pragma unroll
      for (int j = 0; j < 4; ++j)
        acc[i][j] = __builtin_amdgcn_mfma_f32_16x16x32_bf16(af[i], bfr[j], acc[i][j], 0, 0, 0);
  }

  // epilogue: D layout col=lane&15, row=quad*4+reg
#pragma unroll
  for (int i = 0; i < 4; ++i) {
#pragma unroll
    for (int j = 0; j < 4; ++j) {
      long col = n0 + wn + j * 16 + i16;
      float bv = bias[col];
#pragma unroll
      for (int r = 0; r < 4; ++r) {
        long row = m0 + wm + i * 16 + quad * 4 + r;
        float v = acc[i][j][r] + bv;
        if (act == 1) v = fmaxf(v, 0.0f);
        else if (act == 2) v = tanhf(v);
        if (outf32) ((float*)C)[row * N + col] = v;
        else        ((bf16*)C)[row * N + col] = (bf16)v;
      }
    }
  }
}

// ---------------- attention (per-b block): masked softmax over 12 keys ----------------
__global__ __launch_bounds__(256) void attn_kernel(
    const bf16* __restrict__ QKV, const int* __restrict__ Lg, bf16* __restrict__ AO)
{
  const int bl  = blockIdx.x;
  const int tid = threadIdx.x;
  const int L   = Lg[bl];
  const bf16* base = QKV + (long)bl * 12 * 2304;
  __shared__ bf16 kx[12 * 768];
  __shared__ bf16 vx[12 * 768];
  __shared__ float att[8][12][12];
  for (int t = tid; t < 12 * 768; t += 256) {
    int s = t / 768, c = t - s * 768;
    kx[t] = base[(long)s * 2304 + 768 + c];
    vx[t] = base[(long)s * 2304 + 1536 + c];
  }
  __syncthreads();
  for (int t = tid; t < 8 * 12 * 12; t += 256) {
    int h = t / 144, rem = t - h * 144, i = rem / 12, j = rem - (rem / 12) * 12;
    float sc = -1e9f;
    if (j < L) {
      const bf16* q = base + (long)i * 2304 + h * 96;
      const bf16* k = kx + j * 768 + h * 96;
      float a = 0.0f;
      for (int d = 0; d < 96; ++d) a += (float)q[d] * (float)k[d];
      sc = a * 0.10206207261596575f;  // 1/sqrt(96)
    }
    att[h][i][j] = sc;
  }
  __syncthreads();
  for (int t = tid; t < 96; t += 256) {
    int h = t / 12, i = t - h * 12;
    float mx = -3e38f;
#pragma unroll
    for (int j = 0; j < 12; ++j) mx = fmaxf(mx, att[h][i][j]);
    float e[12]; float sum = 0.0f;
#pragma unroll
    for (int j = 0; j < 12; ++j) { e[j] = expf(att[h][i][j] - mx); sum += e[j]; }
    float inv = 1.0f / sum;
#pragma unroll
    for (int j = 0; j < 12; ++j) att[h][i][j] = e[j] * inv;
  }
  __syncthreads();
  for (int t = tid; t < 12 * 768; t += 256) {
    int i = t / 768, c = t - i * 768, h = c / 96;
    float a = 0.0f;
#pragma unroll
    for (int j = 0; j < 12; ++j) a += att[h][i][j] * (float)vx[j * 768 + c];
    AO[(long)bl * 12 * 768 + t] = (bf16)a;
  }
}

// ---------------- LN1: X = LN(gseq + WoO) ----------------
__global__ __launch_bounds__(256) void ln1_kernel(
    const bf16* __restrict__ WoO, const bf16* __restrict__ gseq,
    const float* __restrict__ gam, const float* __restrict__ bet,
    bf16* __restrict__ X)
{
  const long row = blockIdx.x;
  const int tid = threadIdx.x;
  __shared__ float red[8];
  float v[3]; float s = 0.0f, ss = 0.0f;
#pragma unroll
  for (int u = 0; u < 3; ++u) {
    int c = tid + u * 256;
    float x = (float)WoO[row * 768 + c] + (float)gseq[row * 768 + c];
    v[u] = x; s += x; ss += x * x;
  }
  block_sum2(s, ss, red);
  float mu  = s * (1.0f / 768.0f);
  float var = ss * (1.0f / 768.0f) - mu * mu;
  float inv = 1.0f / sqrtf(var + 1e-5f);
#pragma unroll
  for (int u = 0; u < 3; ++u) {
    int c = tid + u * 256;
    X[row * 768 + c] = (bf16)((v[u] - mu) * inv * gam[c] + bet[c]);
  }
}

// ---------------- LN2 + masked mean pool -> x_g ----------------
__global__ __launch_bounds__(256) void ln2pool_kernel(
    const bf16* __restrict__ X, const bf16* __restrict__ FFo,
    const float* __restrict__ gam, const float* __restrict__ bet,
    const int* __restrict__ Lg, float* __restrict__ xg)
{
  const int bl = blockIdx.x;
  const int tid = threadIdx.x;
  const int L = Lg[bl];
  __shared__ float red[8];
  float p0 = 0.0f, p1 = 0.0f, p2 = 0.0f;
  for (int s = 0; s < L; ++s) {
    long row = (long)bl * 12 + s;
    float v[3]; float sm = 0.0f, sq = 0.0f;
#pragma unroll
    for (int u = 0; u < 3; ++u) {
      int c = tid + u * 256;
      float x = (float)X[row * 768 + c] + (float)FFo[row * 768 + c];
      v[u] = x; sm += x; sq += x * x;
    }
    block_sum2(sm, sq, red);
    float mu  = sm * (1.0f / 768.0f);
    float var = sq * (1.0f / 768.0f) - mu * mu;
    float inv = 1.0f / sqrtf(var + 1e-5f);
    p0 += (v[0] - mu) * inv * gam[tid]       + bet[tid];
    p1 += (v[1] - mu) * inv * gam[tid + 256] + bet[tid + 256];
    p2 += (v[2] - mu) * inv * gam[tid + 512] + bet[tid + 512];
  }
  float dn = 1.0f / (float)L;
  xg[(long)bl * 768 + tid]       = p0 * dn;
  xg[(long)bl * 768 + tid + 256] = p1 * dn;
  xg[(long)bl * 768 + tid + 512] = p2 * dn;
}

// ---------------- final: 3-way gate + mix ----------------
__global__ __launch_bounds__(256) void final_kernel(
    const float* __restrict__ xd, const float* __restrict__ xl, const float* __restrict__ xg,
    const float* __restrict__ Wg, const float* __restrict__ bg,
    float* __restrict__ out, int b0)
{
  const int bl = blockIdx.x;
  const int tid = threadIdx.x;
  __shared__ float red[12];
  float l0 = 0.0f, l1 = 0.0f, l2 = 0.0f;
  for (int u = tid; u < 768; u += 256) {
    float pd = xd[(long)bl * 768 + u];
    float pl = xl[(long)bl * 768 + u];
    float pg = xg[(long)bl * 768 + u];
    l0 += pd * Wg[u * 3 + 0] + pl * Wg[(u + 768) * 3 + 0] + pg * Wg[(u + 1536) * 3 + 0];
    l1 += pd * Wg[u * 3 + 1] + pl * Wg[(u + 768) * 3 + 1] + pg * Wg[(u + 1536) * 3 + 1];
    l2 += pd * Wg[u * 3 + 2] + pl * Wg[(u + 768) * 3 + 2] + pg * Wg[(u + 1536) * 3 + 2];
  }
#pragma unroll
  for (int o = 32; o; o >>= 1) {
    l0 += __shfl_xor(l0, o, 64);
    l1 += __shfl_xor(l1, o, 64);
    l2 += __shfl_xor(l2, o, 64);
  }
  if ((tid & 63) == 0) { int w = tid >> 6; red[w * 3] = l0; red[w * 3 + 1] = l1; red[w * 3 + 2] = l2; }
  __syncthreads();
  l0 = red[0] + red[3] + red[6] + red[9]  + bg[0];
  l1 = red[1] + red[4] + red[7] + red[10] + bg[1];
  l2 = red[2] + red[5] + red[8] + red[11] + bg[2];
  float mx = fmaxf(l0, fmaxf(l1, l2));
  float e0 = expf(l0 - mx), e1 = expf(l1 - mx), e2 = expf(l2 - mx);
  float inv = 1.0f / (e0 + e1 + e2);
  e0 *= inv; e1 *= inv; e2 *= inv;
  for (int u = tid; u < 768; u += 256) {
    out[((long)(b0 + bl)) * 768 + u] =
        e0 * xd[(long)bl * 768 + u] + e1 * xl[(long)bl * 768 + u] + e2 * xg[(long)bl * 768 + u];
  }
}

// ---------------- host ----------------
extern "C" void kernel_launch(void* const* d_in, const int* in_sizes, int n_in,
                              void* d_out, int out_size, void* d_ws, size_t ws_size,
                              hipStream_t stream) {
  const float* z    = (const float*)d_in[0];
  const float* buf  = (const float*)d_in[1];
  const int*   mask = (const int*)d_in[2];
  const int*   idxs = (const int*)d_in[3];
  const float* Wq = (const float*)d_in[4];  const float* bq = (const float*)d_in[5];
  const float* Wk = (const float*)d_in[6];  const float* bk = (const float*)d_in[7];
  const float* Wv = (const float*)d_in[8];  const float* bv = (const float*)d_in[9];
  const float* Wo = (const float*)d_in[10]; const float* bo = (const float*)d_in[11];
  const float* ln1g = (const float*)d_in[12]; const float* ln1b = (const float*)d_in[13];
  const float* W1 = (const float*)d_in[14]; const float* b1 = (const float*)d_in[15];
  const float* W2 = (const float*)d_in[16]; const float* b2 = (const float*)d_in[17];
  const float* ln2g = (const float*)d_in[18]; const float* ln2b = (const float*)d_in[19];
  const float* Wd = (const float*)d_in[20]; const float* bd = (const float*)d_in[21];
  const float* Wl = (const float*)d_in[22]; const float* blw = (const float*)d_in[23];
  const float* Wg = (const float*)d_in[24]; const float* bg = (const float*)d_in[25];
  float* out = (float*)d_out;
  (void)in_sizes; (void)n_in; (void)out_size;

  auto rnd = [](size_t x) { return (x + 255) & ~(size_t)255; };

  // fixed (weights) footprint
  size_t fixed = 0;
  fixed += rnd((size_t)2304 * 768 * 2);     // Wqkv_t
  fixed += rnd((size_t)768 * 768 * 2);      // Wo_t
  fixed += rnd((size_t)2048 * 768 * 2);     // W1_t
  fixed += rnd((size_t)768 * 2048 * 2);     // W2_t
  fixed += rnd((size_t)768 * 768 * 2) * 2;  // Wd_t, Wl_t
  fixed += rnd((size_t)2304 * 4);           // bqkv

  auto chunkBytes = [&](int bc) {
    return rnd((size_t)55296 * bc) + 3 * rnd((size_t)18432 * bc)
         + 2 * rnd((size_t)1536 * bc) + rnd((size_t)4 * bc) + 3 * rnd((size_t)3072 * bc);
  };
  int Bc = 8192;
  while (Bc > 128 && fixed + chunkBytes(Bc) > ws_size) Bc >>= 1;

  size_t off = 0;
  auto alloc = [&](size_t n) { void* p = (char*)d_ws + off; off += rnd(n); return p; };
  bf16* Wqkv_t = (bf16*)alloc((size_t)2304 * 768 * 2);
  bf16* Wo_t   = (bf16*)alloc((size_t)768 * 768 * 2);
  bf16* W1_t   = (bf16*)alloc((size_t)2048 * 768 * 2);
  bf16* W2_t   = (bf16*)alloc((size_t)768 * 2048 * 2);
  bf16* Wd_t   = (bf16*)alloc((size_t)768 * 768 * 2);
  bf16* Wl_t   = (bf16*)alloc((size_t)768 * 768 * 2);
  float* bqkv  = (float*)alloc((size_t)2304 * 4);
  bf16* P1 = (bf16*)alloc((size_t)55296 * Bc);  // QKV then FFa
  bf16* P2 = (bf16*)alloc((size_t)18432 * Bc);  // gseq then FFo
  bf16* P3 = (bf16*)alloc((size_t)18432 * Bc);  // AO then X
  bf16* P4 = (bf16*)alloc((size_t)18432 * Bc);  // WoO
  bf16* zb    = (bf16*)alloc((size_t)1536 * Bc);
  bf16* lpool = (bf16*)alloc((size_t)1536 * Bc);
  int*  Lg    = (int*)alloc((size_t)4 * Bc);
  float* xd   = (float*)alloc((size_t)3072 * Bc);
  float* xl   = (float*)alloc((size_t)3072 * Bc);
  float* xg   = (float*)alloc((size_t)3072 * Bc);

  // weight prep (every call; cheap)
  transpose_bf16<<<dim3(24, 24), 256, 0, stream>>>(Wq, Wqkv_t,                 768, 768);
  transpose_bf16<<<dim3(24, 24), 256, 0, stream>>>(Wk, Wqkv_t + 768 * 768,     768, 768);
  transpose_bf16<<<dim3(24, 24), 256, 0, stream>>>(Wv, Wqkv_t + 2 * 768 * 768, 768, 768);
  transpose_bf16<<<dim3(24, 24), 256, 0, stream>>>(Wo, Wo_t, 768, 768);
  transpose_bf16<<<dim3(64, 24), 256, 0, stream>>>(W1, W1_t, 768, 2048);
  transpose_bf16<<<dim3(24, 64), 256, 0, stream>>>(W2, W2_t, 2048, 768);
  transpose_bf16<<<dim3(24, 24), 256, 0, stream>>>(Wd, Wd_t, 768, 768);
  transpose_bf16<<<dim3(24, 24), 256, 0, stream>>>(Wl, Wl_t, 768, 768);
  pack3_kernel<<<9, 256, 0, stream>>>(bq, bk, bv, bqkv);

  for (int b0 = 0; b0 < B_TOT; b0 += Bc) {
    const int Mrows = 12 * Bc;
    prep_kernel<<<Bc, 256, 0, stream>>>(z, buf, mask, idxs, P2, lpool, zb, Lg, b0);
    // QKV = gseq @ Wqkv
    gemm_bt<<<dim3(2304 / 128, Mrows / 128), 256, 0, stream>>>(P2, Wqkv_t, bqkv, P1, 768, 2304, 0, 0);
    attn_kernel<<<Bc, 256, 0, stream>>>(P1, Lg, P3);
    // WoO = AO @ Wo
    gemm_bt<<<dim3(768 / 128, Mrows / 128), 256, 0, stream>>>(P3, Wo_t, bo, P4, 768, 768, 0, 0);
    // X = LN1(gseq + WoO)   (writes P3, AO dead)
    ln1_kernel<<<Mrows, 256, 0, stream>>>(P4, P2, ln1g, ln1b, P3);
    // FFa = relu(X @ W1)    (writes P1, QKV dead)
    gemm_bt<<<dim3(2048 / 128, Mrows / 128), 256, 0, stream>>>(P3, W1_t, b1, P1, 768, 2048, 1, 0);
    // FFo = FFa @ W2        (writes P2, gseq dead)
    gemm_bt<<<dim3(768 / 128, Mrows / 128), 256, 0, stream>>>(P1, W2_t, b2, P2, 2048, 768, 0, 0);
    ln2pool_kernel<<<Bc, 256, 0, stream>>>(P3, P2, ln2g, ln2b, Lg, xg);
    // x_d = tanh(z @ Wd + bd), x_l = tanh(lpool @ Wl + bl)
    gemm_bt<<<dim3(768 / 128, Bc / 128), 256, 0, stream>>>(zb,    Wd_t, bd,  xd, 768, 768, 2, 1);
    gemm_bt<<<dim3(768 / 128, Bc / 128), 256, 0, stream>>>(lpool, Wl_t, blw, xl, 768, 768, 2, 1);
    final_kernel<<<Bc, 256, 0, stream>>>(xd, xl, xg, Wg, bg, out, b0);
  }
}

// Round 2
// 1798.368 us; speedup vs baseline: 1.4422x; 1.4422x over previous
//
#include <hip/hip_runtime.h>
#include <cstdint>
#include <cstddef>

typedef __bf16 bf16;
typedef __attribute__((ext_vector_type(8))) __bf16 bf16x8;
typedef __attribute__((ext_vector_type(4))) float f32x4;

#define B_TOT 8192

// ---------------- async global->LDS (16B per lane) ----------------
__device__ __forceinline__ void gload16(const void* g, void* l) {
  __builtin_amdgcn_global_load_lds(
      (__attribute__((address_space(1))) void*)g,
      (__attribute__((address_space(3))) void*)l, 16, 0, 0);
}

// ---------------- block reduction helper (256 threads, 4 waves) ----------------
__device__ __forceinline__ void block_sum2(float& a, float& b, float* lds8) {
#pragma unroll
  for (int o = 32; o; o >>= 1) {
    a += __shfl_xor(a, o, 64);
    b += __shfl_xor(b, o, 64);
  }
  int w = threadIdx.x >> 6;
  if ((threadIdx.x & 63) == 0) { lds8[w] = a; lds8[4 + w] = b; }
  __syncthreads();
  a = lds8[0] + lds8[1] + lds8[2] + lds8[3];
  b = lds8[4] + lds8[5] + lds8[6] + lds8[7];
  __syncthreads();
}

// ---------------- scan: per-b length L = min(nv,11)+1, exclusive prefix base, total ----------------
__global__ __launch_bounds__(1024) void scan_kernel(
    const int* __restrict__ mask, int* __restrict__ Lg, int* __restrict__ base,
    int* __restrict__ meta, int b0, int Bc)
{
  __shared__ int tsum[1024];
  const int t = threadIdx.x;
  const int per = Bc >> 10;  // Bc/1024 (Bc is a power-of-two >= 1024)
  int l[8];
  int s = 0;
  for (int u = 0; u < per; ++u) {
    int b = t * per + u;
    const int* mp = mask + (long)(b0 + b) * 12;
    int nv = 0;
#pragma unroll
    for (int p = 0; p < 12; ++p) nv += (mp[p] != 0);
    int L = (nv < 11 ? nv : 11) + 1;
    l[u] = L; s += L;
  }
  tsum[t] = s;
  __syncthreads();
  for (int o = 1; o < 1024; o <<= 1) {
    int v = (t >= o) ? tsum[t - o] : 0;
    __syncthreads();
    tsum[t] += v;
    __syncthreads();
  }
  int excl = tsum[t] - s;
  for (int u = 0; u < per; ++u) {
    int b = t * per + u;
    Lg[b] = l[u];
    base[b] = excl;
    excl += l[u];
  }
  if (t == 1023) meta[0] = tsum[1023];
}

// ---------------- prep: compact age-sorted gather; zl = [z ; lpool] ----------------
__global__ __launch_bounds__(256) void prep_kernel(
    const float* __restrict__ z, const float* __restrict__ buf,
    const int* __restrict__ mask, const int* __restrict__ idxs,
    const int* __restrict__ base, bf16* __restrict__ gseq,
    bf16* __restrict__ zl, int b0, int Bc)
{
  const int bl = blockIdx.x;
  const int b  = b0 + bl;
  __shared__ int ord[12];
  __shared__ int s_nv;
  if (threadIdx.x == 0) {
    int id = idxs[b];
    int nv = 0;
    for (int a = 11; a >= 0; --a) {   // ages descending -> oldest first
      int pos = id - a; if (pos < 0) pos += 12;
      if (mask[b * 12 + pos]) ord[nv++] = pos;
    }
    s_nv = nv;
  }
  __syncthreads();
  const int nv = s_nv;
  const int hg = (nv < 11 ? nv : 11);   // valid rows = hg + 1 (last is zero-row or z)
  const int hl = (nv < 4 ? nv : 4);
  const long bs = base[bl];
  const float ld = 1.0f / (float)(hl + 1);
  for (int c = threadIdx.x; c < 768; c += 256) {
    float zv = z[(long)b * 768 + c];
    zl[(long)bl * 768 + c] = (bf16)zv;
    float ls = 0.0f;
    for (int s = 0; s < hg; ++s) {
      float v = buf[((long)b * 12 + ord[s]) * 768 + c];
      gseq[(bs + s) * 768 + c] = (bf16)v;
      if (s < hl) ls += v;
    }
    gseq[(bs + hg) * 768 + c] = (hg == 11) ? (bf16)zv : (bf16)0.0f;
    if (nv >= 4) ls += zv;
    zl[((long)Bc + bl) * 768 + c] = (bf16)(ls * ld);
  }
}

// ---------------- weight transpose f32(K,N) -> bf16(N,K) ----------------
__global__ __launch_bounds__(256) void transpose_bf16(
    const float* __restrict__ W, bf16* __restrict__ Wt, int K, int N)
{
  __shared__ float tile[32][33];
  int bn = blockIdx.x * 32;
  int bk = blockIdx.y * 32;
  int tx = threadIdx.x & 31;
  int ty0 = threadIdx.x >> 5;
  for (int ty = ty0; ty < 32; ty += 8)
    tile[ty][tx] = W[(long)(bk + ty) * N + bn + tx];
  __syncthreads();
  for (int ty = ty0; ty < 32; ty += 8)
    Wt[(long)(bn + ty) * K + bk + tx] = (bf16)tile[tx][ty];
}

__global__ __launch_bounds__(256) void pack3_kernel(
    const float* __restrict__ a, const float* __restrict__ b,
    const float* __restrict__ c, float* __restrict__ out)
{
  int t = blockIdx.x * blockDim.x + threadIdx.x;
  if (t < 768) out[t] = a[t];
  else if (t < 1536) out[t] = b[t - 768];
  else if (t < 2304) out[t] = c[t - 1536];
}

// ---------------- MFMA GEMM: C(M,N) = A(M,K) @ Bt(N,K)^T + bias ----------------
// 128x128 tile, BK=32, XCD-aware y-swizzle, early-exit past mlim[0] rows,
// optional row-split B (rows >= msplit use Bt2/bias2).
__global__ __launch_bounds__(256, 2) void gemm_bt(
    const bf16* __restrict__ A, const bf16* __restrict__ Bt,
    const float* __restrict__ bias, void* __restrict__ C,
    int K, int N, int act, int outf32,
    const int* __restrict__ mlim, int msplit,
    const bf16* __restrict__ Bt2, const float* __restrict__ bias2)
{
  __shared__ __align__(16) bf16 As[128 * 32];
  __shared__ __align__(16) bf16 Bs[128 * 32];
  int gx = gridDim.x, gy = gridDim.y;
  int bx = blockIdx.x, by = blockIdx.y;
  if ((((gx * gy) & 7) == 0) && ((gy & 7) == 0)) {
    int l = bx + gx * by;
    int xcd = l & 7, slot = l >> 3;
    bx = slot % gx;
    by = (slot / gx) * 8 + xcd;   // y == xcd (mod 8): balanced + same-A-tile blocks co-XCD
  }
  const long m0 = (long)by * 128;
  const long n0 = (long)bx * 128;
  if (mlim && m0 >= mlim[0]) return;
  const bf16* Bsel = (m0 >= msplit) ? Bt2 : Bt;
  const float* bsel = (m0 >= msplit) ? bias2 : bias;

  const int tid  = threadIdx.x;
  const int wave = tid >> 6;
  const int lane = tid & 63;
  const int wm = (wave >> 1) * 64;
  const int wn = (wave & 1) * 64;

  const int r0  = (wave * 2 + 0) * 16 + (lane >> 2);
  const int r1  = (wave * 2 + 1) * 16 + (lane >> 2);
  const int kc0 = (lane & 3) ^ ((r0 >> 1) & 3);
  const int kc1 = (lane & 3) ^ ((r1 >> 1) & 3);
  const bf16* Ag0 = A + (m0 + r0) * K + kc0 * 8;
  const bf16* Ag1 = A + (m0 + r1) * K + kc1 * 8;
  const bf16* Bg0 = Bsel + (n0 + r0) * K + kc0 * 8;
  const bf16* Bg1 = Bsel + (n0 + r1) * K + kc1 * 8;
  bf16* Al0 = As + (wave * 2 + 0) * 512 + lane * 8;
  bf16* Al1 = As + (wave * 2 + 1) * 512 + lane * 8;
  bf16* Bl0 = Bs + (wave * 2 + 0) * 512 + lane * 8;
  bf16* Bl1 = Bs + (wave * 2 + 1) * 512 + lane * 8;

  f32x4 acc[4][4] = {};
  const int i16  = lane & 15;
  const int quad = lane >> 4;

  for (int kt = 0; kt < K; kt += 32) {
    __syncthreads();
    gload16(Ag0 + kt, Al0);
    gload16(Ag1 + kt, Al1);
    gload16(Bg0 + kt, Bl0);
    gload16(Bg1 + kt, Bl1);
    __syncthreads();

    bf16x8 af[4], bfr[4];
#pragma unroll
    for (int i = 0; i < 4; ++i) {
      int r = wm + i * 16 + i16;
      af[i] = *(const bf16x8*)(As + r * 32 + ((quad ^ ((r >> 1) & 3)) * 8));
    }
#pragma unroll
    for (int j = 0; j < 4; ++j) {
      int r = wn + j * 16 + i16;
      bfr[j] = *(const bf16x8*)(Bs + r * 32 + ((quad ^ ((r >> 1) & 3)) * 8));
    }
#pragma unroll
    for (int i = 0; i < 4; ++i)
#pragma unroll
      for (int j = 0; j < 4; ++j)
        acc[i][j] = __builtin_amdgcn_mfma_f32_16x16x32_bf16(af[i], bfr[j], acc[i][j], 0, 0, 0);
  }

#pragma unroll
  for (int i = 0; i < 4; ++i) {
#pragma unroll
    for (int j = 0; j < 4; ++j) {
      long col = n0 + wn + j * 16 + i16;
      float bv = bsel[col];
#pragma unroll
      for (int r = 0; r < 4; ++r) {
        long row = m0 + wm + i * 16 + quad * 4 + r;
        float v = acc[i][j][r] + bv;
        if (act == 1) v = fmaxf(v, 0.0f);
        else if (act == 2) v = tanhf(v);
        if (outf32) ((float*)C)[row * N + col] = v;
        else        ((bf16*)C)[row * N + col] = (bf16)v;
      }
    }
  }
}

// ---------------- attention over compact rows (L keys, L queries) ----------------
__global__ __launch_bounds__(256) void attn_kernel(
    const bf16* __restrict__ QKV, const int* __restrict__ base,
    const int* __restrict__ Lg, bf16* __restrict__ AO)
{
  const int bl  = blockIdx.x;
  const int tid = threadIdx.x;
  const int L   = Lg[bl];
  const long bs = base[bl];
  const bf16* qb = QKV + bs * 2304;
  __shared__ bf16 kx[12 * 776];   // row pad 776 to break bank conflicts on score reads
  __shared__ bf16 vx[12 * 776];
  __shared__ float att[8][12][12];
  const int LH = L * 768;
  for (int t = tid; t < LH; t += 256) {
    int s = t / 768, c = t - s * 768;
    kx[s * 776 + c] = qb[(long)s * 2304 + 768 + c];
    vx[s * 776 + c] = qb[(long)s * 2304 + 1536 + c];
  }
  __syncthreads();
  const int LL = L * L;
  for (int t = tid; t < 8 * LL; t += 256) {
    int h = t / LL, r = t - h * LL, i = r / L, j = r - (r / L) * L;
    const bf16x8* q = (const bf16x8*)(qb + (long)i * 2304 + h * 96);
    const bf16x8* k = (const bf16x8*)(kx + j * 776 + h * 96);
    float a = 0.0f;
#pragma unroll
    for (int d = 0; d < 12; ++d) {
      bf16x8 qa = q[d], ka = k[d];
#pragma unroll
      for (int e = 0; e < 8; ++e) a += (float)qa[e] * (float)ka[e];
    }
    att[h][i][j] = a * 0.10206207261596575f;  // 1/sqrt(96)
  }
  __syncthreads();
  for (int t = tid; t < 8 * L; t += 256) {
    int h = t / L, i = t - (t / L) * L;
    float mx = -3e38f;
    for (int j = 0; j < L; ++j) mx = fmaxf(mx, att[h][i][j]);
    float sum = 0.0f;
    for (int j = 0; j < L; ++j) { float e = __expf(att[h][i][j] - mx); att[h][i][j] = e; sum += e; }
    float inv = 1.0f / sum;
    for (int j = 0; j < L; ++j) att[h][i][j] *= inv;
  }
  __syncthreads();
  for (int t = tid; t < LH; t += 256) {
    int i = t / 768, c = t - i * 768, h = c / 96;
    float a = 0.0f;
    for (int j = 0; j < L; ++j) a += att[h][i][j] * (float)vx[j * 776 + c];
    AO[(bs + i) * 768 + c] = (bf16)a;
  }
}

// ---------------- LN1: X = LN(gseq + WoO), compact rows ----------------
__global__ __launch_bounds__(256) void ln1_kernel(
    const bf16* __restrict__ WoO, const bf16* __restrict__ gseq,
    const float* __restrict__ gam, const float* __restrict__ bet,
    bf16* __restrict__ X, const int* __restrict__ meta)
{
  const long row = blockIdx.x;
  if (row >= meta[0]) return;
  const int tid = threadIdx.x;
  __shared__ float red[8];
  float v[3]; float s = 0.0f, ss = 0.0f;
#pragma unroll
  for (int u = 0; u < 3; ++u) {
    int c = tid + u * 256;
    float x = (float)WoO[row * 768 + c] + (float)gseq[row * 768 + c];
    v[u] = x; s += x; ss += x * x;
  }
  block_sum2(s, ss, red);
  float mu  = s * (1.0f / 768.0f);
  float var = ss * (1.0f / 768.0f) - mu * mu;
  float inv = 1.0f / sqrtf(var + 1e-5f);
#pragma unroll
  for (int u = 0; u < 3; ++u) {
    int c = tid + u * 256;
    X[row * 768 + c] = (bf16)((v[u] - mu) * inv * gam[c] + bet[c]);
  }
}

// ---------------- LN2 + mean pool over compact rows -> x_g ----------------
__global__ __launch_bounds__(256) void ln2pool_kernel(
    const bf16* __restrict__ X, const bf16* __restrict__ FFo,
    const float* __restrict__ gam, const float* __restrict__ bet,
    const int* __restrict__ base, const int* __restrict__ Lg,
    float* __restrict__ xg)
{
  const int bl = blockIdx.x;
  const int tid = threadIdx.x;
  const int L = Lg[bl];
  const long bs = base[bl];
  __shared__ float red[8];
  float p0 = 0.0f, p1 = 0.0f, p2 = 0.0f;
  for (int s = 0; s < L; ++s) {
    long row = bs + s;
    float v[3]; float sm = 0.0f, sq = 0.0f;
#pragma unroll
    for (int u = 0; u < 3; ++u) {
      int c = tid + u * 256;
      float x = (float)X[row * 768 + c] + (float)FFo[row * 768 + c];
      v[u] = x; sm += x; sq += x * x;
    }
    block_sum2(sm, sq, red);
    float mu  = sm * (1.0f / 768.0f);
    float var = sq * (1.0f / 768.0f) - mu * mu;
    float inv = 1.0f / sqrtf(var + 1e-5f);
    p0 += (v[0] - mu) * inv * gam[tid]       + bet[tid];
    p1 += (v[1] - mu) * inv * gam[tid + 256] + bet[tid + 256];
    p2 += (v[2] - mu) * inv * gam[tid + 512] + bet[tid + 512];
  }
  float dn = 1.0f / (float)L;
  xg[(long)bl * 768 + tid]       = p0 * dn;
  xg[(long)bl * 768 + tid + 256] = p1 * dn;
  xg[(long)bl * 768 + tid + 512] = p2 * dn;
}

// ---------------- final: 3-way gate + mix ----------------
__global__ __launch_bounds__(256) void final_kernel(
    const float* __restrict__ xdl, const float* __restrict__ xg,
    const float* __restrict__ Wg, const float* __restrict__ bg,
    float* __restrict__ out, int b0, int Bc)
{
  const int bl = blockIdx.x;
  const int tid = threadIdx.x;
  __shared__ float red[12];
  const float* xd = xdl + (long)bl * 768;
  const float* xl = xdl + ((long)Bc + bl) * 768;
  const float* xgp = xg + (long)bl * 768;
  float l0 = 0.0f, l1 = 0.0f, l2 = 0.0f;
  for (int u = tid; u < 768; u += 256) {
    float pd = xd[u], pl = xl[u], pg = xgp[u];
    l0 += pd * Wg[u * 3 + 0] + pl * Wg[(u + 768) * 3 + 0] + pg * Wg[(u + 1536) * 3 + 0];
    l1 += pd * Wg[u * 3 + 1] + pl * Wg[(u + 768) * 3 + 1] + pg * Wg[(u + 1536) * 3 + 1];
    l2 += pd * Wg[u * 3 + 2] + pl * Wg[(u + 768) * 3 + 2] + pg * Wg[(u + 1536) * 3 + 2];
  }
#pragma unroll
  for (int o = 32; o; o >>= 1) {
    l0 += __shfl_xor(l0, o, 64);
    l1 += __shfl_xor(l1, o, 64);
    l2 += __shfl_xor(l2, o, 64);
  }
  if ((tid & 63) == 0) { int w = tid >> 6; red[w * 3] = l0; red[w * 3 + 1] = l1; red[w * 3 + 2] = l2; }
  __syncthreads();
  l0 = red[0] + red[3] + red[6] + red[9]  + bg[0];
  l1 = red[1] + red[4] + red[7] + red[10] + bg[1];
  l2 = red[2] + red[5] + red[8] + red[11] + bg[2];
  float mx = fmaxf(l0, fmaxf(l1, l2));
  float e0 = __expf(l0 - mx), e1 = __expf(l1 - mx), e2 = __expf(l2 - mx);
  float inv = 1.0f / (e0 + e1 + e2);
  e0 *= inv; e1 *= inv; e2 *= inv;
  for (int u = tid; u < 768; u += 256) {
    out[((long)(b0 + bl)) * 768 + u] = e0 * xd[u] + e1 * xl[u] + e2 * xgp[u];
  }
}

// ---------------- host ----------------
extern "C" void kernel_launch(void* const* d_in, const int* in_sizes, int n_in,
                              void* d_out, int out_size, void* d_ws, size_t ws_size,
                              hipStream_t stream) {
  const float* z    = (const float*)d_in[0];
  const float* buf  = (const float*)d_in[1];
  const int*   mask = (const int*)d_in[2];
  const int*   idxs = (const int*)d_in[3];
  const float* Wq = (const float*)d_in[4];  const float* bq = (const float*)d_in[5];
  const float* Wk = (const float*)d_in[6];  const float* bk = (const float*)d_in[7];
  const float* Wv = (const float*)d_in[8];  const float* bv = (const float*)d_in[9];
  const float* Wo = (const float*)d_in[10]; const float* bo = (const float*)d_in[11];
  const float* ln1g = (const float*)d_in[12]; const float* ln1b = (const float*)d_in[13];
  const float* W1 = (const float*)d_in[14]; const float* b1 = (const float*)d_in[15];
  const float* W2 = (const float*)d_in[16]; const float* b2 = (const float*)d_in[17];
  const float* ln2g = (const float*)d_in[18]; const float* ln2b = (const float*)d_in[19];
  const float* Wd = (const float*)d_in[20]; const float* bd = (const float*)d_in[21];
  const float* Wl = (const float*)d_in[22]; const float* blw = (const float*)d_in[23];
  const float* Wg = (const float*)d_in[24]; const float* bg = (const float*)d_in[25];
  float* out = (float*)d_out;
  (void)in_sizes; (void)n_in; (void)out_size;

  auto rnd = [](size_t x) { return (x + 255) & ~(size_t)255; };

  size_t fixed = 0;
  fixed += rnd((size_t)2304 * 768 * 2);
  fixed += rnd((size_t)768 * 768 * 2);
  fixed += rnd((size_t)2048 * 768 * 2);
  fixed += rnd((size_t)768 * 2048 * 2);
  fixed += rnd((size_t)768 * 768 * 2) * 2;
  fixed += rnd((size_t)2304 * 4) + 256;

  auto chunkBytes = [&](size_t bc) {
    return rnd((size_t)55296 * bc) + 3 * rnd((size_t)18432 * bc)
         + rnd((size_t)3072 * bc) + rnd((size_t)6144 * bc) + rnd((size_t)3072 * bc)
         + 2 * rnd((size_t)4 * bc);
  };
  int Bc = 8192;
  while (Bc > 1024 && fixed + chunkBytes(Bc) > ws_size) Bc >>= 1;

  size_t off = 0;
  auto alloc = [&](size_t n) { void* p = (char*)d_ws + off; off += rnd(n); return p; };
  bf16* Wqkv_t = (bf16*)alloc((size_t)2304 * 768 * 2);
  bf16* Wo_t   = (bf16*)alloc((size_t)768 * 768 * 2);
  bf16* W1_t   = (bf16*)alloc((size_t)2048 * 768 * 2);
  bf16* W2_t   = (bf16*)alloc((size_t)768 * 2048 * 2);
  bf16* Wd_t   = (bf16*)alloc((size_t)768 * 768 * 2);
  bf16* Wl_t   = (bf16*)alloc((size_t)768 * 768 * 2);
  float* bqkv  = (float*)alloc((size_t)2304 * 4);
  int*  meta   = (int*)alloc(256);
  bf16* P1 = (bf16*)alloc((size_t)55296 * Bc);  // QKV then FFa
  bf16* P2 = (bf16*)alloc((size_t)18432 * Bc);  // gseq then FFo
  bf16* P3 = (bf16*)alloc((size_t)18432 * Bc);  // AO then X
  bf16* P4 = (bf16*)alloc((size_t)18432 * Bc);  // WoO
  bf16* zl   = (bf16*)alloc((size_t)3072 * Bc); // [z ; lpool]
  float* xdl = (float*)alloc((size_t)6144 * Bc);
  float* xg  = (float*)alloc((size_t)3072 * Bc);
  int*  Lg   = (int*)alloc((size_t)4 * Bc);
  int*  base = (int*)alloc((size_t)4 * Bc);

  transpose_bf16<<<dim3(24, 24), 256, 0, stream>>>(Wq, Wqkv_t,                 768, 768);
  transpose_bf16<<<dim3(24, 24), 256, 0, stream>>>(Wk, Wqkv_t + 768 * 768,     768, 768);
  transpose_bf16<<<dim3(24, 24), 256, 0, stream>>>(Wv, Wqkv_t + 2 * 768 * 768, 768, 768);
  transpose_bf16<<<dim3(24, 24), 256, 0, stream>>>(Wo, Wo_t, 768, 768);
  transpose_bf16<<<dim3(64, 24), 256, 0, stream>>>(W1, W1_t, 768, 2048);
  transpose_bf16<<<dim3(24, 64), 256, 0, stream>>>(W2, W2_t, 2048, 768);
  transpose_bf16<<<dim3(24, 24), 256, 0, stream>>>(Wd, Wd_t, 768, 768);
  transpose_bf16<<<dim3(24, 24), 256, 0, stream>>>(Wl, Wl_t, 768, 768);
  pack3_kernel<<<9, 256, 0, stream>>>(bq, bk, bv, bqkv);

  const int BIG = 0x7fffffff;
  for (int b0 = 0; b0 < B_TOT; b0 += Bc) {
    const int Ycap = (12 * Bc) / 128;   // worst-case row tiles
    scan_kernel<<<1, 1024, 0, stream>>>(mask, Lg, base, meta, b0, Bc);
    prep_kernel<<<Bc, 256, 0, stream>>>(z, buf, mask, idxs, base, P2, zl, b0, Bc);
    // QKV = gseq @ Wqkv
    gemm_bt<<<dim3(18, Ycap), 256, 0, stream>>>(P2, Wqkv_t, bqkv, P1, 768, 2304, 0, 0, meta, BIG, nullptr, nullptr);
    attn_kernel<<<Bc, 256, 0, stream>>>(P1, base, Lg, P3);
    // WoO = AO @ Wo
    gemm_bt<<<dim3(6, Ycap), 256, 0, stream>>>(P3, Wo_t, bo, P4, 768, 768, 0, 0, meta, BIG, nullptr, nullptr);
    // X = LN1(gseq + WoO)
    ln1_kernel<<<12 * Bc, 256, 0, stream>>>(P4, P2, ln1g, ln1b, P3, meta);
    // FFa = relu(X @ W1)
    gemm_bt<<<dim3(16, Ycap), 256, 0, stream>>>(P3, W1_t, b1, P1, 768, 2048, 1, 0, meta, BIG, nullptr, nullptr);
    // FFo = FFa @ W2
    gemm_bt<<<dim3(6, Ycap), 256, 0, stream>>>(P1, W2_t, b2, P2, 2048, 768, 0, 0, meta, BIG, nullptr, nullptr);
    ln2pool_kernel<<<Bc, 256, 0, stream>>>(P3, P2, ln2g, ln2b, base, Lg, xg);
    // xdl = tanh([z;lpool] @ [Wd|Wl] + [bd|bl])  (row-split B)
    gemm_bt<<<dim3(6, (2 * Bc) / 128), 256, 0, stream>>>(zl, Wd_t, bd, xdl, 768, 768, 2, 1, nullptr, Bc, Wl_t, blw);
    final_kernel<<<Bc, 256, 0, stream>>>(xdl, xg, Wg, bg, out, b0, Bc);
  }
}

// Round 3
// 1591.783 us; speedup vs baseline: 1.6294x; 1.1298x over previous
//
#include <hip/hip_runtime.h>
#include <cstdint>
#include <cstddef>

typedef __bf16 bf16;
typedef __attribute__((ext_vector_type(8))) __bf16 bf16x8;
typedef __attribute__((ext_vector_type(4))) float f32x4;

#define B_TOT 8192

// ---------------- async global->LDS (16B per lane) ----------------
__device__ __forceinline__ void gload16(const void* g, void* l) {
  __builtin_amdgcn_global_load_lds(
      (__attribute__((address_space(1))) void*)g,
      (__attribute__((address_space(3))) void*)l, 16, 0, 0);
}

// ---------------- block reduction helper (256 threads, 4 waves) ----------------
__device__ __forceinline__ void block_sum2(float& a, float& b, float* lds8) {
#pragma unroll
  for (int o = 32; o; o >>= 1) {
    a += __shfl_xor(a, o, 64);
    b += __shfl_xor(b, o, 64);
  }
  int w = threadIdx.x >> 6;
  if ((threadIdx.x & 63) == 0) { lds8[w] = a; lds8[4 + w] = b; }
  __syncthreads();
  a = lds8[0] + lds8[1] + lds8[2] + lds8[3];
  b = lds8[4] + lds8[5] + lds8[6] + lds8[7];
  __syncthreads();
}

// ---------------- scan phase 1: per-block exclusive scan of L ----------------
__global__ __launch_bounds__(256) void scan1_kernel(
    const int* __restrict__ mask, int* __restrict__ Lg, int* __restrict__ lbase,
    int* __restrict__ btot, int b0)
{
  __shared__ int ts[256];
  const int t = threadIdx.x;
  const int b = blockIdx.x * 256 + t;
  const int* mp = mask + (long)(b0 + b) * 12;
  int nv = 0;
#pragma unroll
  for (int p = 0; p < 12; ++p) nv += (mp[p] != 0);
  int L = (nv < 11 ? nv : 11) + 1;
  ts[t] = L;
  __syncthreads();
  for (int o = 1; o < 256; o <<= 1) {
    int v = (t >= o) ? ts[t - o] : 0;
    __syncthreads();
    ts[t] += v;
    __syncthreads();
  }
  Lg[b] = L;
  lbase[b] = ts[t] - L;
  if (t == 255) btot[blockIdx.x] = ts[255];
}

// ---------------- scan phase 2: scan of block totals (nb <= 32, trivial) ----------------
__global__ __launch_bounds__(64) void scan2_kernel(
    const int* __restrict__ btot, int* __restrict__ boff, int* __restrict__ meta, int nb)
{
  if (threadIdx.x == 0) {
    int acc = 0;
    for (int i = 0; i < nb; ++i) { int v = btot[i]; boff[i] = acc; acc += v; }
    meta[0] = acc;
  }
}

// ---------------- prep: compact age-sorted gather; zl = [z ; lpool]; fbase ----------------
__global__ __launch_bounds__(256) void prep_kernel(
    const float* __restrict__ z, const float* __restrict__ buf,
    const int* __restrict__ mask, const int* __restrict__ idxs,
    const int* __restrict__ lbase, const int* __restrict__ boff,
    int* __restrict__ fbase, bf16* __restrict__ gseq,
    bf16* __restrict__ zl, int b0, int Bc)
{
  const int bl = blockIdx.x;
  const int b  = b0 + bl;
  __shared__ int ord[12];
  __shared__ int s_nv;
  if (threadIdx.x == 0) {
    int id = idxs[b];
    int nv = 0;
    for (int a = 11; a >= 0; --a) {   // ages descending -> oldest first
      int pos = id - a; if (pos < 0) pos += 12;
      if (mask[b * 12 + pos]) ord[nv++] = pos;
    }
    s_nv = nv;
  }
  const long bs = (long)lbase[bl] + boff[bl >> 8];
  if (threadIdx.x == 0) fbase[bl] = (int)bs;
  __syncthreads();
  const int nv = s_nv;
  const int hg = (nv < 11 ? nv : 11);   // valid rows = hg + 1 (last is zero-row or z)
  const int hl = (nv < 4 ? nv : 4);
  const float ld = 1.0f / (float)(hl + 1);
  for (int c = threadIdx.x; c < 768; c += 256) {
    float zv = z[(long)b * 768 + c];
    zl[(long)bl * 768 + c] = (bf16)zv;
    float ls = 0.0f;
    for (int s = 0; s < hg; ++s) {
      float v = buf[((long)b * 12 + ord[s]) * 768 + c];
      gseq[(bs + s) * 768 + c] = (bf16)v;
      if (s < hl) ls += v;
    }
    gseq[(bs + hg) * 768 + c] = (hg == 11) ? (bf16)zv : (bf16)0.0f;
    if (nv >= 4) ls += zv;
    zl[((long)Bc + bl) * 768 + c] = (bf16)(ls * ld);
  }
}

// ---------------- weight transpose f32(K,N) -> bf16(N,K) ----------------
__global__ __launch_bounds__(256) void transpose_bf16(
    const float* __restrict__ W, bf16* __restrict__ Wt, int K, int N)
{
  __shared__ float tile[32][33];
  int bn = blockIdx.x * 32;
  int bk = blockIdx.y * 32;
  int tx = threadIdx.x & 31;
  int ty0 = threadIdx.x >> 5;
  for (int ty = ty0; ty < 32; ty += 8)
    tile[ty][tx] = W[(long)(bk + ty) * N + bn + tx];
  __syncthreads();
  for (int ty = ty0; ty < 32; ty += 8)
    Wt[(long)(bn + ty) * K + bk + tx] = (bf16)tile[tx][ty];
}

__global__ __launch_bounds__(256) void pack3_kernel(
    const float* __restrict__ a, const float* __restrict__ b,
    const float* __restrict__ c, float* __restrict__ out)
{
  int t = blockIdx.x * blockDim.x + threadIdx.x;
  if (t < 768) out[t] = a[t];
  else if (t < 1536) out[t] = b[t - 768];
  else if (t < 2304) out[t] = c[t - 1536];
}

// ---------------- MFMA GEMM: C(M,N) = A(M,K) @ Bt(N,K)^T + bias ----------------
// 128x128 tile, BK=64, XCD-aware y-swizzle, early-exit past mlim[0] rows,
// optional row-split B (rows >= msplit use Bt2/bias2).
// LDS chunk swizzle: LDS(r, cpos) holds global chunk cpos ^ (r&7).
__global__ __launch_bounds__(256, 2) void gemm_bt(
    const bf16* __restrict__ A, const bf16* __restrict__ Bt,
    const float* __restrict__ bias, void* __restrict__ C,
    int K, int N, int act, int outf32,
    const int* __restrict__ mlim, int msplit,
    const bf16* __restrict__ Bt2, const float* __restrict__ bias2)
{
  __shared__ __align__(16) bf16 smem[2 * 128 * 64];
  bf16* As = smem;
  bf16* Bs = smem + 128 * 64;
  int gx = gridDim.x, gy = gridDim.y;
  int bx = blockIdx.x, by = blockIdx.y;
  if ((gy & 7) == 0) {
    int l = bx + gx * by;
    int xcd = l & 7, slot = l >> 3;
    bx = slot % gx;
    by = (slot / gx) * 8 + xcd;   // y == xcd (mod 8): same-A-row blocks co-XCD
  }
  const long m0 = (long)by * 128;
  const long n0 = (long)bx * 128;
  if (mlim && m0 >= mlim[0]) return;
  const bf16* Bsel = (m0 >= msplit) ? Bt2 : Bt;
  const float* bsel = (m0 >= msplit) ? bias2 : bias;

  const int tid  = threadIdx.x;
  const int wave = tid >> 6;
  const int lane = tid & 63;
  const int wm = (wave >> 1) * 64;
  const int wn = (wave & 1) * 64;
  const int i16  = lane & 15;
  const int quad = lane >> 4;
  const int l8 = lane >> 3;
  const int c7 = lane & 7;

  // staging: wave w stages rows [w*32, w*32+32) of both tiles; 4 segs of 8 rows
  const int csrc = c7 ^ l8;   // source chunk for swizzled LDS layout
  const bf16* Ag[4]; const bf16* Bg[4];
  bf16* Al[4]; bf16* Bl[4];
#pragma unroll
  for (int u = 0; u < 4; ++u) {
    int r = wave * 32 + u * 8 + l8;
    Ag[u] = A    + (m0 + r) * K + csrc * 8;
    Bg[u] = Bsel + (n0 + r) * K + csrc * 8;
    Al[u] = As + (wave * 32 + u * 8) * 64 + lane * 8;
    Bl[u] = Bs + (wave * 32 + u * 8) * 64 + lane * 8;
  }

  f32x4 acc[4][4] = {};

  for (int kt = 0; kt < K; kt += 64) {
    __syncthreads();
#pragma unroll
    for (int u = 0; u < 4; ++u) {
      gload16(Ag[u] + kt, Al[u]);
      gload16(Bg[u] + kt, Bl[u]);
    }
    __syncthreads();
#pragma unroll
    for (int s = 0; s < 2; ++s) {
      const int cofs = ((s << 2) | quad) ^ c7;   // frag rows have r&7 == c7
      bf16x8 af[4], bfr[4];
#pragma unroll
      for (int i = 0; i < 4; ++i)
        af[i] = *(const bf16x8*)(As + (wm + i * 16 + i16) * 64 + cofs * 8);
#pragma unroll
      for (int j = 0; j < 4; ++j)
        bfr[j] = *(const bf16x8*)(Bs + (wn + j * 16 + i16) * 64 + cofs * 8);
#pragma unroll
      for (int i = 0; i < 4; ++i)
#pragma unroll
        for (int j = 0; j < 4; ++j)
          acc[i][j] = __builtin_amdgcn_mfma_f32_16x16x32_bf16(af[i], bfr[j], acc[i][j], 0, 0, 0);
    }
  }

  if (!outf32) {
    // vectorized bf16 epilogue: acc -> LDS (chunk-swizzled) -> 16B global stores
    __syncthreads();
    bf16* Cs = smem;   // 128 x 128 bf16 = 32 KB
#pragma unroll
    for (int j = 0; j < 4; ++j) {
      int col = wn + j * 16 + i16;
      int c8s = (col >> 3) ^ (quad << 1);
      int clo = col & 7;
      float bv = bsel[n0 + col];
#pragma unroll
      for (int i = 0; i < 4; ++i) {
#pragma unroll
        for (int r = 0; r < 4; ++r) {
          int row = wm + i * 16 + quad * 4 + r;   // (row>>2)&3 == quad
          float v = acc[i][j][r] + bv;
          if (act == 1) v = fmaxf(v, 0.0f);
          Cs[row * 128 + c8s * 8 + clo] = (bf16)v;
        }
      }
    }
    __syncthreads();
    bf16* Cg = (bf16*)C;
#pragma unroll
    for (int u = 0; u < 8; ++u) {
      int g = u * 256 + tid;
      int row = g >> 4, c8 = g & 15;
      int c8s = c8 ^ (((row >> 2) & 3) << 1);
      *(bf16x8*)(Cg + (m0 + row) * N + n0 + c8 * 8) =
          *(const bf16x8*)(Cs + row * 128 + c8s * 8);
    }
  } else {
#pragma unroll
    for (int i = 0; i < 4; ++i) {
#pragma unroll
      for (int j = 0; j < 4; ++j) {
        long col = n0 + wn + j * 16 + i16;
        float bv = bsel[col];
#pragma unroll
        for (int r = 0; r < 4; ++r) {
          long row = m0 + wm + i * 16 + quad * 4 + r;
          float v = acc[i][j][r] + bv;
          if (act == 1) v = fmaxf(v, 0.0f);
          else if (act == 2) v = tanhf(v);
          ((float*)C)[row * N + col] = v;
        }
      }
    }
  }
}

// ---------------- attention over compact rows (L keys, L queries) ----------------
__global__ __launch_bounds__(256) void attn_kernel(
    const bf16* __restrict__ QKV, const int* __restrict__ fbase,
    const int* __restrict__ Lg, bf16* __restrict__ AO)
{
  const int bl  = blockIdx.x;
  const int tid = threadIdx.x;
  const int L   = Lg[bl];
  const long bs = fbase[bl];
  const bf16* qb = QKV + bs * 2304;
  __shared__ bf16 kx[12 * 776];   // row pad 776 to break bank conflicts
  __shared__ bf16 vx[12 * 776];
  __shared__ float att[8][12][12];
  const int LH = L * 768;
  for (int t = tid; t < LH; t += 256) {
    int s = t / 768, c = t - s * 768;
    kx[s * 776 + c] = qb[(long)s * 2304 + 768 + c];
    vx[s * 776 + c] = qb[(long)s * 2304 + 1536 + c];
  }
  __syncthreads();
  const int LL = L * L;
  for (int t = tid; t < 8 * LL; t += 256) {
    int h = t / LL, r = t - h * LL, i = r / L, j = r - (r / L) * L;
    const bf16x8* q = (const bf16x8*)(qb + (long)i * 2304 + h * 96);
    const bf16x8* k = (const bf16x8*)(kx + j * 776 + h * 96);
    float a = 0.0f;
#pragma unroll
    for (int d = 0; d < 12; ++d) {
      bf16x8 qa = q[d], ka = k[d];
#pragma unroll
      for (int e = 0; e < 8; ++e) a += (float)qa[e] * (float)ka[e];
    }
    att[h][i][j] = a * 0.10206207261596575f;  // 1/sqrt(96)
  }
  __syncthreads();
  for (int t = tid; t < 8 * L; t += 256) {
    int h = t / L, i = t - (t / L) * L;
    float mx = -3e38f;
    for (int j = 0; j < L; ++j) mx = fmaxf(mx, att[h][i][j]);
    float sum = 0.0f;
    for (int j = 0; j < L; ++j) { float e = __expf(att[h][i][j] - mx); att[h][i][j] = e; sum += e; }
    float inv = 1.0f / sum;
    for (int j = 0; j < L; ++j) att[h][i][j] *= inv;
  }
  __syncthreads();
  for (int t = tid; t < LH; t += 256) {
    int i = t / 768, c = t - i * 768, h = c / 96;
    float a = 0.0f;
    for (int j = 0; j < L; ++j) a += att[h][i][j] * (float)vx[j * 776 + c];
    AO[(bs + i) * 768 + c] = (bf16)a;
  }
}

// ---------------- LN1: X = LN(gseq + WoO), compact rows ----------------
__global__ __launch_bounds__(256) void ln1_kernel(
    const bf16* __restrict__ WoO, const bf16* __restrict__ gseq,
    const float* __restrict__ gam, const float* __restrict__ bet,
    bf16* __restrict__ X, const int* __restrict__ meta)
{
  const long row = blockIdx.x;
  if (row >= meta[0]) return;
  const int tid = threadIdx.x;
  __shared__ float red[8];
  float v[3]; float s = 0.0f, ss = 0.0f;
#pragma unroll
  for (int u = 0; u < 3; ++u) {
    int c = tid + u * 256;
    float x = (float)WoO[row * 768 + c] + (float)gseq[row * 768 + c];
    v[u] = x; s += x; ss += x * x;
  }
  block_sum2(s, ss, red);
  float mu  = s * (1.0f / 768.0f);
  float var = ss * (1.0f / 768.0f) - mu * mu;
  float inv = 1.0f / sqrtf(var + 1e-5f);
#pragma unroll
  for (int u = 0; u < 3; ++u) {
    int c = tid + u * 256;
    X[row * 768 + c] = (bf16)((v[u] - mu) * inv * gam[c] + bet[c]);
  }
}

// ---------------- LN2 + mean pool + gate + mix -> out ----------------
__global__ __launch_bounds__(256) void ln2gate_kernel(
    const bf16* __restrict__ X, const bf16* __restrict__ FFo,
    const float* __restrict__ gam, const float* __restrict__ bet,
    const int* __restrict__ fbase, const int* __restrict__ Lg,
    const float* __restrict__ xdl, const float* __restrict__ Wg,
    const float* __restrict__ bg, float* __restrict__ out, int b0, int Bc)
{
  const int bl = blockIdx.x;
  const int tid = threadIdx.x;
  const int L = Lg[bl];
  const long bs = fbase[bl];
  __shared__ float red[8];
  __shared__ float red3[12];
  float p0 = 0.0f, p1 = 0.0f, p2 = 0.0f;
  for (int s = 0; s < L; ++s) {
    long row = bs + s;
    float v[3]; float sm = 0.0f, sq = 0.0f;
#pragma unroll
    for (int u = 0; u < 3; ++u) {
      int c = tid + u * 256;
      float x = (float)X[row * 768 + c] + (float)FFo[row * 768 + c];
      v[u] = x; sm += x; sq += x * x;
    }
    block_sum2(sm, sq, red);
    float mu  = sm * (1.0f / 768.0f);
    float var = sq * (1.0f / 768.0f) - mu * mu;
    float inv = 1.0f / sqrtf(var + 1e-5f);
    p0 += (v[0] - mu) * inv * gam[tid]       + bet[tid];
    p1 += (v[1] - mu) * inv * gam[tid + 256] + bet[tid + 256];
    p2 += (v[2] - mu) * inv * gam[tid + 512] + bet[tid + 512];
  }
  float dn = 1.0f / (float)L;
  p0 *= dn; p1 *= dn; p2 *= dn;
  const float* xd = xdl + (long)bl * 768;
  const float* xl = xdl + ((long)Bc + bl) * 768;
  float xd0 = xd[tid], xd1 = xd[tid + 256], xd2 = xd[tid + 512];
  float xl0 = xl[tid], xl1 = xl[tid + 256], xl2 = xl[tid + 512];
  float l0 = 0.0f, l1 = 0.0f, l2 = 0.0f;
#pragma unroll
  for (int r = 0; r < 3; ++r) {
    float lr = xd0 * Wg[tid * 3 + r] + xd1 * Wg[(tid + 256) * 3 + r] + xd2 * Wg[(tid + 512) * 3 + r]
             + xl0 * Wg[(768 + tid) * 3 + r] + xl1 * Wg[(1024 + tid) * 3 + r] + xl2 * Wg[(1280 + tid) * 3 + r]
             + p0 * Wg[(1536 + tid) * 3 + r] + p1 * Wg[(1792 + tid) * 3 + r] + p2 * Wg[(2048 + tid) * 3 + r];
    if (r == 0) l0 = lr; else if (r == 1) l1 = lr; else l2 = lr;
  }
#pragma unroll
  for (int o = 32; o; o >>= 1) {
    l0 += __shfl_xor(l0, o, 64);
    l1 += __shfl_xor(l1, o, 64);
    l2 += __shfl_xor(l2, o, 64);
  }
  if ((tid & 63) == 0) { int w = tid >> 6; red3[w * 3] = l0; red3[w * 3 + 1] = l1; red3[w * 3 + 2] = l2; }
  __syncthreads();
  l0 = red3[0] + red3[3] + red3[6] + red3[9]  + bg[0];
  l1 = red3[1] + red3[4] + red3[7] + red3[10] + bg[1];
  l2 = red3[2] + red3[5] + red3[8] + red3[11] + bg[2];
  float mx = fmaxf(l0, fmaxf(l1, l2));
  float e0 = __expf(l0 - mx), e1 = __expf(l1 - mx), e2 = __expf(l2 - mx);
  float inv = 1.0f / (e0 + e1 + e2);
  e0 *= inv; e1 *= inv; e2 *= inv;
  float* op = out + (long)(b0 + bl) * 768;
  op[tid]       = e0 * xd0 + e1 * xl0 + e2 * p0;
  op[tid + 256] = e0 * xd1 + e1 * xl1 + e2 * p1;
  op[tid + 512] = e0 * xd2 + e1 * xl2 + e2 * p2;
}

// ---------------- host ----------------
extern "C" void kernel_launch(void* const* d_in, const int* in_sizes, int n_in,
                              void* d_out, int out_size, void* d_ws, size_t ws_size,
                              hipStream_t stream) {
  const float* z    = (const float*)d_in[0];
  const float* buf  = (const float*)d_in[1];
  const int*   mask = (const int*)d_in[2];
  const int*   idxs = (const int*)d_in[3];
  const float* Wq = (const float*)d_in[4];  const float* bq = (const float*)d_in[5];
  const float* Wk = (const float*)d_in[6];  const float* bk = (const float*)d_in[7];
  const float* Wv = (const float*)d_in[8];  const float* bv = (const float*)d_in[9];
  const float* Wo = (const float*)d_in[10]; const float* bo = (const float*)d_in[11];
  const float* ln1g = (const float*)d_in[12]; const float* ln1b = (const float*)d_in[13];
  const float* W1 = (const float*)d_in[14]; const float* b1 = (const float*)d_in[15];
  const float* W2 = (const float*)d_in[16]; const float* b2 = (const float*)d_in[17];
  const float* ln2g = (const float*)d_in[18]; const float* ln2b = (const float*)d_in[19];
  const float* Wd = (const float*)d_in[20]; const float* bd = (const float*)d_in[21];
  const float* Wl = (const float*)d_in[22]; const float* blw = (const float*)d_in[23];
  const float* Wg = (const float*)d_in[24]; const float* bg = (const float*)d_in[25];
  float* out = (float*)d_out;
  (void)in_sizes; (void)n_in; (void)out_size;

  auto rnd = [](size_t x) { return (x + 255) & ~(size_t)255; };

  size_t fixed = 0;
  fixed += rnd((size_t)2304 * 768 * 2);
  fixed += rnd((size_t)768 * 768 * 2);
  fixed += rnd((size_t)2048 * 768 * 2);
  fixed += rnd((size_t)768 * 2048 * 2);
  fixed += rnd((size_t)768 * 768 * 2) * 2;
  fixed += rnd((size_t)2304 * 4) + 256 + 512 + 512;

  auto chunkBytes = [&](size_t bc) {
    return rnd((size_t)55296 * bc) + 3 * rnd((size_t)18432 * bc)
         + rnd((size_t)3072 * bc) + rnd((size_t)6144 * bc)
         + 3 * rnd((size_t)4 * bc);
  };
  int Bc = 8192;
  while (Bc > 1024 && fixed + chunkBytes(Bc) > ws_size) Bc >>= 1;

  size_t off = 0;
  auto alloc = [&](size_t n) { void* p = (char*)d_ws + off; off += rnd(n); return p; };
  bf16* Wqkv_t = (bf16*)alloc((size_t)2304 * 768 * 2);
  bf16* Wo_t   = (bf16*)alloc((size_t)768 * 768 * 2);
  bf16* W1_t   = (bf16*)alloc((size_t)2048 * 768 * 2);
  bf16* W2_t   = (bf16*)alloc((size_t)768 * 2048 * 2);
  bf16* Wd_t   = (bf16*)alloc((size_t)768 * 768 * 2);
  bf16* Wl_t   = (bf16*)alloc((size_t)768 * 768 * 2);
  float* bqkv  = (float*)alloc((size_t)2304 * 4);
  int*  meta   = (int*)alloc(256);
  int*  btot   = (int*)alloc(512);
  int*  boff   = (int*)alloc(512);
  bf16* P1 = (bf16*)alloc((size_t)55296 * Bc);  // QKV then FFa
  bf16* P2 = (bf16*)alloc((size_t)18432 * Bc);  // gseq then FFo
  bf16* P3 = (bf16*)alloc((size_t)18432 * Bc);  // AO then X
  bf16* P4 = (bf16*)alloc((size_t)18432 * Bc);  // WoO
  bf16* zl   = (bf16*)alloc((size_t)3072 * Bc); // [z ; lpool]
  float* xdl = (float*)alloc((size_t)6144 * Bc);
  int*  Lg    = (int*)alloc((size_t)4 * Bc);
  int*  lbase = (int*)alloc((size_t)4 * Bc);
  int*  fbase = (int*)alloc((size_t)4 * Bc);

  transpose_bf16<<<dim3(24, 24), 256, 0, stream>>>(Wq, Wqkv_t,                 768, 768);
  transpose_bf16<<<dim3(24, 24), 256, 0, stream>>>(Wk, Wqkv_t + 768 * 768,     768, 768);
  transpose_bf16<<<dim3(24, 24), 256, 0, stream>>>(Wv, Wqkv_t + 2 * 768 * 768, 768, 768);
  transpose_bf16<<<dim3(24, 24), 256, 0, stream>>>(Wo, Wo_t, 768, 768);
  transpose_bf16<<<dim3(64, 24), 256, 0, stream>>>(W1, W1_t, 768, 2048);
  transpose_bf16<<<dim3(24, 64), 256, 0, stream>>>(W2, W2_t, 2048, 768);
  transpose_bf16<<<dim3(24, 24), 256, 0, stream>>>(Wd, Wd_t, 768, 768);
  transpose_bf16<<<dim3(24, 24), 256, 0, stream>>>(Wl, Wl_t, 768, 768);
  pack3_kernel<<<9, 256, 0, stream>>>(bq, bk, bv, bqkv);

  const int BIG = 0x7fffffff;
  for (int b0 = 0; b0 < B_TOT; b0 += Bc) {
    const int Ycap = (12 * Bc) / 128;   // worst-case row tiles
    scan1_kernel<<<Bc / 256, 256, 0, stream>>>(mask, Lg, lbase, btot, b0);
    scan2_kernel<<<1, 64, 0, stream>>>(btot, boff, meta, Bc / 256);
    prep_kernel<<<Bc, 256, 0, stream>>>(z, buf, mask, idxs, lbase, boff, fbase, P2, zl, b0, Bc);
    // xdl = tanh([z;lpool] @ [Wd|Wl] + [bd|bl])  (row-split B)
    gemm_bt<<<dim3(6, (2 * Bc) / 128), 256, 0, stream>>>(zl, Wd_t, bd, xdl, 768, 768, 2, 1, nullptr, Bc, Wl_t, blw);
    // QKV = gseq @ Wqkv
    gemm_bt<<<dim3(18, Ycap), 256, 0, stream>>>(P2, Wqkv_t, bqkv, P1, 768, 2304, 0, 0, meta, BIG, nullptr, nullptr);
    attn_kernel<<<Bc, 256, 0, stream>>>(P1, fbase, Lg, P3);
    // WoO = AO @ Wo
    gemm_bt<<<dim3(6, Ycap), 256, 0, stream>>>(P3, Wo_t, bo, P4, 768, 768, 0, 0, meta, BIG, nullptr, nullptr);
    // X = LN1(gseq + WoO)
    ln1_kernel<<<12 * Bc, 256, 0, stream>>>(P4, P2, ln1g, ln1b, P3, meta);
    // FFa = relu(X @ W1)
    gemm_bt<<<dim3(16, Ycap), 256, 0, stream>>>(P3, W1_t, b1, P1, 768, 2048, 1, 0, meta, BIG, nullptr, nullptr);
    // FFo = FFa @ W2
    gemm_bt<<<dim3(6, Ycap), 256, 0, stream>>>(P1, W2_t, b2, P2, 2048, 768, 0, 0, meta, BIG, nullptr, nullptr);
    // LN2 + pool + gate + mix
    ln2gate_kernel<<<Bc, 256, 0, stream>>>(P3, P2, ln2g, ln2b, fbase, Lg, xdl, Wg, bg, out, b0, Bc);
  }
}